// Round 11
// baseline (101.540 us; speedup 1.0000x reference)
//
#include <hip/hip_runtime.h>
#include <cmath>

// SE block: windowed mean-pool -> softsign(mW1+b1) -> sigmoid(softsign(hW2+b2)) -> gate x.
// B=32, M=2048, D=512, H=64, WIN=16 (M % WIN == 0, so reference edge-pad is a no-op).
// R10 = R4 champion structure (x "in registers", NW=2, 56.4us) + R6's aliased 12.8KB LDS
//       + __launch_bounds__(256,6). R6 proved the aliasing correct but its (256,8) bound
//       forced VGPR 60->32 (massive spill, WRITE 235MB). (256,6) caps VGPR at ~85 — above
//       the natural ~60 — so no spill, while LDS 12.8KB allows 6 blocks/CU (R4: 33KB -> 4).
//       More resident blocks = more cross-block phase overlap, the only mechanism that has
//       moved this kernel (every residency drop regressed: R8 2/CU=62us, R9 spills=82us).
//       Aliasing lifetimes (all separated by barriers):
//         region A (8KB): s_ps [ph1..ph1b] | s_hp [ph2..ph2b] | s_gp [ph3..ph3b]
//         region B (4KB): s_m4 [ph1b..ph2] | s_g4 [ph3b..ph4]
//         s_h (512B) standalone.

constexpr int WIN = 16;
constexpr int D   = 512;
constexpr int H   = 64;
constexpr int TPB = 256;
constexpr int NW  = 2;                 // windows per block

__global__ __launch_bounds__(TPB, 6) void se_block_kernel(
    const float* __restrict__ x,
    const float* __restrict__ W1,
    const float* __restrict__ b1,
    const float* __restrict__ W2,
    const float* __restrict__ b2,
    float* __restrict__ y)
{
    const int tid = threadIdx.x;
    // Block handles NW consecutive windows: contiguous NW*WIN*D floats.
    const size_t base = (size_t)blockIdx.x * (size_t)(NW * WIN * D);
    const float4* __restrict__ xw = reinterpret_cast<const float4*>(x + base);
    float4*       __restrict__ yw = reinterpret_cast<float4*>(y + base);

    const float4* __restrict__ W1f4 = reinterpret_cast<const float4*>(W1); // [512] rows x 16 f4
    const float4* __restrict__ W2f4 = reinterpret_cast<const float4*>(W2); // [64] rows x 128 f4
    const float4* __restrict__ b2f4 = reinterpret_cast<const float4*>(b2);

    __shared__ __align__(16) char sA[NW * TPB * 16];      // 8 KB
    __shared__ __align__(16) char sB[NW * (D / 4) * 16];  // 4 KB
    __shared__ float s_h[NW][H];                          // 512 B

    float4* s_ps = reinterpret_cast<float4*>(sA);   // [NW][256]       ph1 -> ph1b
    float4* s_hp = reinterpret_cast<float4*>(sA);   // [16][NW][16]    ph2 -> ph2b
    float4* s_gp = reinterpret_cast<float4*>(sA);   // [2][NW][128]    ph3 -> ph3b
    float4* s_m4 = reinterpret_cast<float4*>(sB);   // [NW][128]       ph1b -> ph2
    float4* s_g4 = reinterpret_cast<float4*>(sB);   // [NW][128]       ph3b -> ph4

    // ---- Load x into registers. Window w, float4 element i*256+tid:
    //      col group c = tid&127, row = 2*i + (tid>>7).
    float4 r[NW][8];
#pragma unroll
    for (int w = 0; w < NW; ++w)
#pragma unroll
        for (int i = 0; i < 8; ++i) r[w][i] = xw[w * 2048 + i * TPB + tid];

    // ================= Phase 1: per-thread partial sums =================
#pragma unroll
    for (int w = 0; w < NW; ++w) {
        float4 ps = r[w][0];
#pragma unroll
        for (int i = 1; i < 8; ++i) {
            ps.x += r[w][i].x; ps.y += r[w][i].y; ps.z += r[w][i].z; ps.w += r[w][i].w;
        }
        s_ps[w * TPB + tid] = ps;
    }
    __syncthreads();

    // ================= Phase 1b: window means =================
    {   // 256 tasks = NW x 128 col-groups
        const int w = tid >> 7;
        const int c = tid & 127;
        const float4 a = s_ps[w * TPB + c];
        const float4 b = s_ps[w * TPB + c + 128];
        const float sc = 1.0f / 16.0f;
        float4 m;
        m.x = (a.x + b.x) * sc; m.y = (a.y + b.y) * sc;
        m.z = (a.z + b.z) * sc; m.w = (a.w + b.w) * sc;
        s_m4[w * 128 + c] = m;
    }
    __syncthreads();

    // ================= Phase 2: h_pre = m @ W1, 16-way k-split, batched over NW ========
    // Thread = (p = tid>>4 k-part, j4 = tid&15). k in [p*32, p*32+32).
    {
        const int p  = tid >> 4;
        const int j4 = tid & 15;
        float4 acc[NW];
#pragma unroll
        for (int w = 0; w < NW; ++w) acc[w] = make_float4(0.f, 0.f, 0.f, 0.f);
#pragma unroll 2
        for (int kk4 = 0; kk4 < 8; ++kk4) {
            const int c4 = p * 8 + kk4;                 // float4 group of k
            const int k  = c4 * 4;
            const float4 w0 = W1f4[(size_t)(k + 0) * 16 + j4];
            const float4 w1 = W1f4[(size_t)(k + 1) * 16 + j4];
            const float4 w2 = W1f4[(size_t)(k + 2) * 16 + j4];
            const float4 w3 = W1f4[(size_t)(k + 3) * 16 + j4];
#pragma unroll
            for (int w = 0; w < NW; ++w) {
                const float4 mv = s_m4[w * 128 + c4];
                acc[w].x = fmaf(mv.x, w0.x, acc[w].x); acc[w].y = fmaf(mv.x, w0.y, acc[w].y);
                acc[w].z = fmaf(mv.x, w0.z, acc[w].z); acc[w].w = fmaf(mv.x, w0.w, acc[w].w);
                acc[w].x = fmaf(mv.y, w1.x, acc[w].x); acc[w].y = fmaf(mv.y, w1.y, acc[w].y);
                acc[w].z = fmaf(mv.y, w1.z, acc[w].z); acc[w].w = fmaf(mv.y, w1.w, acc[w].w);
                acc[w].x = fmaf(mv.z, w2.x, acc[w].x); acc[w].y = fmaf(mv.z, w2.y, acc[w].y);
                acc[w].z = fmaf(mv.z, w2.z, acc[w].z); acc[w].w = fmaf(mv.z, w2.w, acc[w].w);
                acc[w].x = fmaf(mv.w, w3.x, acc[w].x); acc[w].y = fmaf(mv.w, w3.y, acc[w].y);
                acc[w].z = fmaf(mv.w, w3.z, acc[w].z); acc[w].w = fmaf(mv.w, w3.w, acc[w].w);
            }
        }
        __syncthreads();   // s_m4 reads done; s_ps fully dead -> region A reusable as s_hp
#pragma unroll
        for (int w = 0; w < NW; ++w) s_hp[(p * NW + w) * 16 + j4] = acc[w];
    }
    __syncthreads();

    // ================= Phase 2b: reduce 16 k-parts, +b1, softsign =================
    if (tid < NW * H) {
        const float* s_hpf = reinterpret_cast<const float*>(s_hp);
        const int w = tid >> 6;
        const int j = tid & 63;
        float s = b1[j];
#pragma unroll
        for (int p = 0; p < 16; ++p) s += s_hpf[(p * NW + w) * H + j];
        s_h[w][j] = s / (1.0f + fabsf(s));
    }
    __syncthreads();

    // ================= Phase 3: g_pre = h @ W2, 2-way j-split, batched =================
    // Thread = (q = tid>>7 j-part, d4 = tid&127). j in [q*32, q*32+32).
    {
        const float4* s_h4 = reinterpret_cast<const float4*>(&s_h[0][0]); // [NW][16]
        const int q  = tid >> 7;
        const int d4 = tid & 127;
        float4 acc[NW];
#pragma unroll
        for (int w = 0; w < NW; ++w) acc[w] = make_float4(0.f, 0.f, 0.f, 0.f);
#pragma unroll 2
        for (int jj4 = 0; jj4 < 8; ++jj4) {
            const int jg = q * 8 + jj4;                 // float4 group of j
            const int j  = jg * 4;
            const float4 w0 = W2f4[(size_t)(j + 0) * 128 + d4];
            const float4 w1 = W2f4[(size_t)(j + 1) * 128 + d4];
            const float4 w2 = W2f4[(size_t)(j + 2) * 128 + d4];
            const float4 w3 = W2f4[(size_t)(j + 3) * 128 + d4];
#pragma unroll
            for (int w = 0; w < NW; ++w) {
                const float4 hv = s_h4[w * 16 + jg];
                acc[w].x = fmaf(hv.x, w0.x, acc[w].x); acc[w].y = fmaf(hv.x, w0.y, acc[w].y);
                acc[w].z = fmaf(hv.x, w0.z, acc[w].z); acc[w].w = fmaf(hv.x, w0.w, acc[w].w);
                acc[w].x = fmaf(hv.y, w1.x, acc[w].x); acc[w].y = fmaf(hv.y, w1.y, acc[w].y);
                acc[w].z = fmaf(hv.y, w1.z, acc[w].z); acc[w].w = fmaf(hv.y, w1.w, acc[w].w);
                acc[w].x = fmaf(hv.z, w2.x, acc[w].x); acc[w].y = fmaf(hv.z, w2.y, acc[w].y);
                acc[w].z = fmaf(hv.z, w2.z, acc[w].z); acc[w].w = fmaf(hv.z, w2.w, acc[w].w);
                acc[w].x = fmaf(hv.w, w3.x, acc[w].x); acc[w].y = fmaf(hv.w, w3.y, acc[w].y);
                acc[w].z = fmaf(hv.w, w3.z, acc[w].z); acc[w].w = fmaf(hv.w, w3.w, acc[w].w);
            }
        }
        __syncthreads();   // s_hp reads (ph2b) done -> region A reusable as s_gp
#pragma unroll
        for (int w = 0; w < NW; ++w) s_gp[(q * NW + w) * 128 + d4] = acc[w];
    }
    __syncthreads();

    // ================= Phase 3b: reduce 2 j-parts, +b2, softsign, sigmoid =================
    {
        const int w  = tid >> 7;
        const int d4 = tid & 127;
        const float4 a  = s_gp[(0 * NW + w) * 128 + d4];
        const float4 b  = s_gp[(1 * NW + w) * 128 + d4];
        const float4 bb = b2f4[d4];
        float4 s;
        s.x = a.x + b.x + bb.x; s.y = a.y + b.y + bb.y;
        s.z = a.z + b.z + bb.z; s.w = a.w + b.w + bb.w;
        s.x = s.x / (1.0f + fabsf(s.x)); s.y = s.y / (1.0f + fabsf(s.y));
        s.z = s.z / (1.0f + fabsf(s.z)); s.w = s.w / (1.0f + fabsf(s.w));
        float4 g;
        g.x = 1.0f / (1.0f + __expf(-s.x)); g.y = 1.0f / (1.0f + __expf(-s.y));
        g.z = 1.0f / (1.0f + __expf(-s.z)); g.w = 1.0f / (1.0f + __expf(-s.w));
        __syncthreads();   // s_m4 reads (ph2) long done -> region B reusable as s_g4
        s_g4[w * 128 + d4] = g;
    }
    __syncthreads();

    // ================= Phase 4: gate from registers, store =================
    {
        const int c = tid & 127;
#pragma unroll
        for (int w = 0; w < NW; ++w) {
            const float4 g = s_g4[w * 128 + c];
#pragma unroll
            for (int i = 0; i < 8; ++i) {
                float4 o;
                o.x = r[w][i].x * g.x; o.y = r[w][i].y * g.y;
                o.z = r[w][i].z * g.z; o.w = r[w][i].w * g.w;
                yw[w * 2048 + i * TPB + tid] = o;
            }
        }
    }
}

extern "C" void kernel_launch(void* const* d_in, const int* in_sizes, int n_in,
                              void* d_out, int out_size, void* d_ws, size_t ws_size,
                              hipStream_t stream) {
    const float* x  = (const float*)d_in[0];
    const float* W1 = (const float*)d_in[1];
    const float* b1 = (const float*)d_in[2];
    const float* W2 = (const float*)d_in[3];
    const float* b2 = (const float*)d_in[4];
    float* y = (float*)d_out;

    const int n_windows = in_sizes[0] / (WIN * D);   // B * (M/WIN) = 4096
    const int n_blocks  = n_windows / NW;            // 2048
    se_block_kernel<<<dim3(n_blocks), dim3(TPB), 0, stream>>>(x, W1, b1, W2, b2, y);
}

// Round 12
// 57.243 us; speedup vs baseline: 1.7738x; 1.7738x over previous
//
#include <hip/hip_runtime.h>
#include <cmath>

// SE block: windowed mean-pool -> softsign(mW1+b1) -> sigmoid(softsign(hW2+b2)) -> gate x.
// B=32, M=2048, D=512, H=64, WIN=16 (M % WIN == 0, so reference edge-pad is a no-op).
// R11 = R4 champion EXACTLY (launch_bounds(256,4): natural VGPR=60, no spill, 56.4us)
//       + R10's aliased 12.8KB LDS (correctness proven in R10).
//       At VGPR=60 (<=64) HW allows 8 waves/SIMD; LDS 12.8KB allows >8 blocks/CU;
//       grid 2048 = 8 blocks/CU exactly. R6/R10 failed ONLY because bounds (256,8)/(256,6)
//       poisoned regalloc (VGPR 32/40 -> spills); (256,4) is proven safe at VGPR=60.
//       Aliasing lifetimes (all separated by barriers):
//         region A (8KB): s_ps [ph1..ph1b] | s_hp [ph2..ph2b] | s_gp [ph3..ph3b]
//         region B (4KB): s_m4 [ph1b..ph2] | s_g4 [ph3b..ph4]
//         s_h (512B) standalone.

constexpr int WIN = 16;
constexpr int D   = 512;
constexpr int H   = 64;
constexpr int TPB = 256;
constexpr int NW  = 2;                 // windows per block

__global__ __launch_bounds__(TPB, 4) void se_block_kernel(
    const float* __restrict__ x,
    const float* __restrict__ W1,
    const float* __restrict__ b1,
    const float* __restrict__ W2,
    const float* __restrict__ b2,
    float* __restrict__ y)
{
    const int tid = threadIdx.x;
    // Block handles NW consecutive windows: contiguous NW*WIN*D floats.
    const size_t base = (size_t)blockIdx.x * (size_t)(NW * WIN * D);
    const float4* __restrict__ xw = reinterpret_cast<const float4*>(x + base);
    float4*       __restrict__ yw = reinterpret_cast<float4*>(y + base);

    const float4* __restrict__ W1f4 = reinterpret_cast<const float4*>(W1); // [512] rows x 16 f4
    const float4* __restrict__ W2f4 = reinterpret_cast<const float4*>(W2); // [64] rows x 128 f4
    const float4* __restrict__ b2f4 = reinterpret_cast<const float4*>(b2);

    __shared__ __align__(16) char sA[NW * TPB * 16];      // 8 KB
    __shared__ __align__(16) char sB[NW * (D / 4) * 16];  // 4 KB
    __shared__ float s_h[NW][H];                          // 512 B

    float4* s_ps = reinterpret_cast<float4*>(sA);   // [NW][256]       ph1 -> ph1b
    float4* s_hp = reinterpret_cast<float4*>(sA);   // [16][NW][16]    ph2 -> ph2b
    float4* s_gp = reinterpret_cast<float4*>(sA);   // [2][NW][128]    ph3 -> ph3b
    float4* s_m4 = reinterpret_cast<float4*>(sB);   // [NW][128]       ph1b -> ph2
    float4* s_g4 = reinterpret_cast<float4*>(sB);   // [NW][128]       ph3b -> ph4

    // ---- Load x into registers. Window w, float4 element i*256+tid:
    //      col group c = tid&127, row = 2*i + (tid>>7).
    float4 r[NW][8];
#pragma unroll
    for (int w = 0; w < NW; ++w)
#pragma unroll
        for (int i = 0; i < 8; ++i) r[w][i] = xw[w * 2048 + i * TPB + tid];

    // ================= Phase 1: per-thread partial sums =================
#pragma unroll
    for (int w = 0; w < NW; ++w) {
        float4 ps = r[w][0];
#pragma unroll
        for (int i = 1; i < 8; ++i) {
            ps.x += r[w][i].x; ps.y += r[w][i].y; ps.z += r[w][i].z; ps.w += r[w][i].w;
        }
        s_ps[w * TPB + tid] = ps;
    }
    __syncthreads();

    // ================= Phase 1b: window means =================
    {   // 256 tasks = NW x 128 col-groups
        const int w = tid >> 7;
        const int c = tid & 127;
        const float4 a = s_ps[w * TPB + c];
        const float4 b = s_ps[w * TPB + c + 128];
        const float sc = 1.0f / 16.0f;
        float4 m;
        m.x = (a.x + b.x) * sc; m.y = (a.y + b.y) * sc;
        m.z = (a.z + b.z) * sc; m.w = (a.w + b.w) * sc;
        s_m4[w * 128 + c] = m;
    }
    __syncthreads();

    // ================= Phase 2: h_pre = m @ W1, 16-way k-split, batched over NW ========
    // Thread = (p = tid>>4 k-part, j4 = tid&15). k in [p*32, p*32+32).
    {
        const int p  = tid >> 4;
        const int j4 = tid & 15;
        float4 acc[NW];
#pragma unroll
        for (int w = 0; w < NW; ++w) acc[w] = make_float4(0.f, 0.f, 0.f, 0.f);
#pragma unroll 2
        for (int kk4 = 0; kk4 < 8; ++kk4) {
            const int c4 = p * 8 + kk4;                 // float4 group of k
            const int k  = c4 * 4;
            const float4 w0 = W1f4[(size_t)(k + 0) * 16 + j4];
            const float4 w1 = W1f4[(size_t)(k + 1) * 16 + j4];
            const float4 w2 = W1f4[(size_t)(k + 2) * 16 + j4];
            const float4 w3 = W1f4[(size_t)(k + 3) * 16 + j4];
#pragma unroll
            for (int w = 0; w < NW; ++w) {
                const float4 mv = s_m4[w * 128 + c4];
                acc[w].x = fmaf(mv.x, w0.x, acc[w].x); acc[w].y = fmaf(mv.x, w0.y, acc[w].y);
                acc[w].z = fmaf(mv.x, w0.z, acc[w].z); acc[w].w = fmaf(mv.x, w0.w, acc[w].w);
                acc[w].x = fmaf(mv.y, w1.x, acc[w].x); acc[w].y = fmaf(mv.y, w1.y, acc[w].y);
                acc[w].z = fmaf(mv.y, w1.z, acc[w].z); acc[w].w = fmaf(mv.y, w1.w, acc[w].w);
                acc[w].x = fmaf(mv.z, w2.x, acc[w].x); acc[w].y = fmaf(mv.z, w2.y, acc[w].y);
                acc[w].z = fmaf(mv.z, w2.z, acc[w].z); acc[w].w = fmaf(mv.z, w2.w, acc[w].w);
                acc[w].x = fmaf(mv.w, w3.x, acc[w].x); acc[w].y = fmaf(mv.w, w3.y, acc[w].y);
                acc[w].z = fmaf(mv.w, w3.z, acc[w].z); acc[w].w = fmaf(mv.w, w3.w, acc[w].w);
            }
        }
        __syncthreads();   // s_m4 reads done; s_ps fully dead -> region A reusable as s_hp
#pragma unroll
        for (int w = 0; w < NW; ++w) s_hp[(p * NW + w) * 16 + j4] = acc[w];
    }
    __syncthreads();

    // ================= Phase 2b: reduce 16 k-parts, +b1, softsign =================
    if (tid < NW * H) {
        const float* s_hpf = reinterpret_cast<const float*>(s_hp);
        const int w = tid >> 6;
        const int j = tid & 63;
        float s = b1[j];
#pragma unroll
        for (int p = 0; p < 16; ++p) s += s_hpf[(p * NW + w) * H + j];
        s_h[w][j] = s / (1.0f + fabsf(s));
    }
    __syncthreads();

    // ================= Phase 3: g_pre = h @ W2, 2-way j-split, batched =================
    // Thread = (q = tid>>7 j-part, d4 = tid&127). j in [q*32, q*32+32).
    {
        const float4* s_h4 = reinterpret_cast<const float4*>(&s_h[0][0]); // [NW][16]
        const int q  = tid >> 7;
        const int d4 = tid & 127;
        float4 acc[NW];
#pragma unroll
        for (int w = 0; w < NW; ++w) acc[w] = make_float4(0.f, 0.f, 0.f, 0.f);
#pragma unroll 2
        for (int jj4 = 0; jj4 < 8; ++jj4) {
            const int jg = q * 8 + jj4;                 // float4 group of j
            const int j  = jg * 4;
            const float4 w0 = W2f4[(size_t)(j + 0) * 128 + d4];
            const float4 w1 = W2f4[(size_t)(j + 1) * 128 + d4];
            const float4 w2 = W2f4[(size_t)(j + 2) * 128 + d4];
            const float4 w3 = W2f4[(size_t)(j + 3) * 128 + d4];
#pragma unroll
            for (int w = 0; w < NW; ++w) {
                const float4 hv = s_h4[w * 16 + jg];
                acc[w].x = fmaf(hv.x, w0.x, acc[w].x); acc[w].y = fmaf(hv.x, w0.y, acc[w].y);
                acc[w].z = fmaf(hv.x, w0.z, acc[w].z); acc[w].w = fmaf(hv.x, w0.w, acc[w].w);
                acc[w].x = fmaf(hv.y, w1.x, acc[w].x); acc[w].y = fmaf(hv.y, w1.y, acc[w].y);
                acc[w].z = fmaf(hv.y, w1.z, acc[w].z); acc[w].w = fmaf(hv.y, w1.w, acc[w].w);
                acc[w].x = fmaf(hv.z, w2.x, acc[w].x); acc[w].y = fmaf(hv.z, w2.y, acc[w].y);
                acc[w].z = fmaf(hv.z, w2.z, acc[w].z); acc[w].w = fmaf(hv.z, w2.w, acc[w].w);
                acc[w].x = fmaf(hv.w, w3.x, acc[w].x); acc[w].y = fmaf(hv.w, w3.y, acc[w].y);
                acc[w].z = fmaf(hv.w, w3.z, acc[w].z); acc[w].w = fmaf(hv.w, w3.w, acc[w].w);
            }
        }
        __syncthreads();   // s_hp reads (ph2b) done -> region A reusable as s_gp
#pragma unroll
        for (int w = 0; w < NW; ++w) s_gp[(q * NW + w) * 128 + d4] = acc[w];
    }
    __syncthreads();

    // ================= Phase 3b: reduce 2 j-parts, +b2, softsign, sigmoid =================
    {
        const int w  = tid >> 7;
        const int d4 = tid & 127;
        const float4 a  = s_gp[(0 * NW + w) * 128 + d4];
        const float4 b  = s_gp[(1 * NW + w) * 128 + d4];
        const float4 bb = b2f4[d4];
        float4 s;
        s.x = a.x + b.x + bb.x; s.y = a.y + b.y + bb.y;
        s.z = a.z + b.z + bb.z; s.w = a.w + b.w + bb.w;
        s.x = s.x / (1.0f + fabsf(s.x)); s.y = s.y / (1.0f + fabsf(s.y));
        s.z = s.z / (1.0f + fabsf(s.z)); s.w = s.w / (1.0f + fabsf(s.w));
        float4 g;
        g.x = 1.0f / (1.0f + __expf(-s.x)); g.y = 1.0f / (1.0f + __expf(-s.y));
        g.z = 1.0f / (1.0f + __expf(-s.z)); g.w = 1.0f / (1.0f + __expf(-s.w));
        __syncthreads();   // s_m4 reads (ph2) long done -> region B reusable as s_g4
        s_g4[w * 128 + d4] = g;
    }
    __syncthreads();

    // ================= Phase 4: gate from registers, store =================
    {
        const int c = tid & 127;
#pragma unroll
        for (int w = 0; w < NW; ++w) {
            const float4 g = s_g4[w * 128 + c];
#pragma unroll
            for (int i = 0; i < 8; ++i) {
                float4 o;
                o.x = r[w][i].x * g.x; o.y = r[w][i].y * g.y;
                o.z = r[w][i].z * g.z; o.w = r[w][i].w * g.w;
                yw[w * 2048 + i * TPB + tid] = o;
            }
        }
    }
}

extern "C" void kernel_launch(void* const* d_in, const int* in_sizes, int n_in,
                              void* d_out, int out_size, void* d_ws, size_t ws_size,
                              hipStream_t stream) {
    const float* x  = (const float*)d_in[0];
    const float* W1 = (const float*)d_in[1];
    const float* b1 = (const float*)d_in[2];
    const float* W2 = (const float*)d_in[3];
    const float* b2 = (const float*)d_in[4];
    float* y = (float*)d_out;

    const int n_windows = in_sizes[0] / (WIN * D);   // B * (M/WIN) = 4096
    const int n_blocks  = n_windows / NW;            // 2048
    se_block_kernel<<<dim3(n_blocks), dim3(TPB), 0, stream>>>(x, W1, b1, W2, b2, y);
}